// Round 19
// baseline (109.507 us; speedup 1.0000x reference)
//
#include <hip/hip_runtime.h>

#define BATCH 2
#define S_LEN 2048
#define NHEADS 16
#define DKV 64
#define HID 1024

typedef __attribute__((ext_vector_type(8))) short s16x8;
typedef __attribute__((ext_vector_type(4))) short s16x4;
typedef __attribute__((ext_vector_type(4))) float f32x4;

__device__ inline unsigned short f2bf(float f) {
    union { float f; unsigned int u; } v; v.f = f;
    unsigned int r = v.u + 0x7fffu + ((v.u >> 16) & 1u);
    return (unsigned short)(r >> 16);
}

__device__ inline s16x8 pack8(float4 a, float4 b) {
    s16x8 r;
    r[0] = (short)f2bf(a.x); r[1] = (short)f2bf(a.y);
    r[2] = (short)f2bf(a.z); r[3] = (short)f2bf(a.w);
    r[4] = (short)f2bf(b.x); r[5] = (short)f2bf(b.y);
    r[6] = (short)f2bf(b.z); r[7] = (short)f2bf(b.w);
    return r;
}

__device__ inline void gload_lds16(const void* g, void* l) {
    __builtin_amdgcn_global_load_lds(
        (const __attribute__((address_space(1))) void*)g,
        (__attribute__((address_space(3))) void*)l, 16, 0, 0);
}

__device__ inline unsigned int cvtpk_bf16(float lo, float hi) {
    unsigned int d;
    asm("v_cvt_pk_bf16_f32 %0, %1, %2" : "=v"(d) : "v"(lo), "v"(hi));
    return d;
}

// Merged prep: [0,2048) x f32->bf16; [2048,5120) w_attn transpose;
// [5120,6144) w_proj transpose.
__global__ __launch_bounds__(256)
void prep_kernel(const float* __restrict__ x, unsigned short* __restrict__ xb,
                 const float* __restrict__ w_attn, unsigned short* __restrict__ waT,
                 const float* __restrict__ w_proj, unsigned short* __restrict__ wpT) {
    __shared__ float tile[32][33];
    const int blk = blockIdx.x;
    const int tid = threadIdx.x;

    if (blk < 2048) {
        int i = blk * 256 + tid;
        const float4* p = (const float4*)(x + (size_t)i * 8);
        float4 a = p[0], b = p[1];
        *(s16x8*)(xb + (size_t)i * 8) = pack8(a, b);
        return;
    }

    const float* in;
    unsigned short* outp;
    int n0, k0, N;
    if (blk < 5120) {
        int idx = blk - 2048;
        N = 3 * HID;
        n0 = (idx % 96) * 32; k0 = (idx / 96) * 32;
        in = w_attn; outp = waT;
    } else {
        int idx = blk - 5120;
        N = HID;
        n0 = (idx % 32) * 32; k0 = (idx / 32) * 32;
        in = w_proj; outp = wpT;
    }
    const int tx = tid & 31, ty = tid >> 5;
    for (int i = ty; i < 32; i += 8)
        tile[i][tx] = in[(size_t)(k0 + i) * N + n0 + tx];
    __syncthreads();
    // widened write: 4 bf16 (b64) per thread
    {
        const int n  = tid >> 3;          // 0..31
        const int kc = (tid & 7) * 4;     // 0..28
        s16x4 pk;
        #pragma unroll
        for (int j = 0; j < 4; j++) pk[j] = (short)f2bf(tile[kc + j][n]);
        *(s16x4*)&outp[(size_t)(n0 + n) * HID + k0 + kc] = pk;
    }
}

// QKV GEMM: BK=32, linear LDS, double-buffered staging, 2D grid (n-fastest).
// Q columns pre-scaled by 0.125*log2e (softmax scale folded into Q).
// Q/K columns -> qkv[M][2H]; V columns -> vT[b][d][s'] key-permuted
// (s' = [s5,s3,s2,s4,s1,s0]) for the zero-shuffle PV in attn.
__global__ __launch_bounds__(256)
void gemm_qkv_kernel(const unsigned short* __restrict__ A, const unsigned short* __restrict__ Bt,
                     const float* __restrict__ bias, unsigned short* __restrict__ qkv,
                     unsigned short* __restrict__ vT, int M, int N, int K) {
    __shared__ __align__(16) unsigned short As[2][128 * 32];
    __shared__ __align__(16) unsigned short Bs[2][128 * 32];

    const int tid  = threadIdx.x;
    const int lane = tid & 63;
    const int wv   = tid >> 6;
    const int wr   = wv >> 1, wc = wv & 1;
    const int m0   = blockIdx.y * 128, n0 = blockIdx.x * 128;

    const int lr = lane & 15;
    const int lg = lane >> 4;
    const int lk = lg * 8;

    const int srow = lane >> 2;
    const int scol = (lane & 3) * 8;

    f32x4 acc[4][4] = {};
    int cur = 0;

    #pragma unroll
    for (int l = 0; l < 2; l++) {
        const int r0 = wv * 32 + l * 16;
        gload_lds16(A  + (size_t)(m0 + r0 + srow) * K + scol, &As[0][r0 * 32]);
        gload_lds16(Bt + (size_t)(n0 + r0 + srow) * K + scol, &Bs[0][r0 * 32]);
    }

    for (int k0 = 0; k0 < K; k0 += 32) {
        __syncthreads();

        if (k0 + 32 < K) {
            #pragma unroll
            for (int l = 0; l < 2; l++) {
                const int r0 = wv * 32 + l * 16;
                gload_lds16(A  + (size_t)(m0 + r0 + srow) * K + k0 + 32 + scol, &As[cur ^ 1][r0 * 32]);
                gload_lds16(Bt + (size_t)(n0 + r0 + srow) * K + k0 + 32 + scol, &Bs[cur ^ 1][r0 * 32]);
            }
        }

        s16x8 af[4], bfr[4];
        #pragma unroll
        for (int mi = 0; mi < 4; mi++)
            af[mi] = *(const s16x8*)&As[cur][(wr * 64 + mi * 16 + lr) * 32 + lk];
        #pragma unroll
        for (int ni = 0; ni < 4; ni++)
            bfr[ni] = *(const s16x8*)&Bs[cur][(wc * 64 + ni * 16 + lr) * 32 + lk];
        #pragma unroll
        for (int mi = 0; mi < 4; mi++)
            #pragma unroll
            for (int ni = 0; ni < 4; ni++)
                acc[mi][ni] = __builtin_amdgcn_mfma_f32_16x16x32_bf16(af[mi], bfr[ni], acc[mi][ni], 0, 0, 0);
        cur ^= 1;
    }

    const bool isV = (n0 >= 2 * HID);
    const float qsc = (n0 < HID) ? 0.18033688f : 1.0f;   // fold softmax scale into Q
    #pragma unroll
    for (int mi = 0; mi < 4; mi++) {
        #pragma unroll
        for (int ni = 0; ni < 4; ni++) {
            int col = n0 + wc * 64 + ni * 16 + lr;
            float bv = bias[col];
            int row0 = m0 + wr * 64 + mi * 16 + lg * 4;
            if (isV) {
                int d = col - 2 * HID;
                int bb = row0 >> 11;
                int s = row0 & (S_LEN - 1);
                int sl = s & 63;
                int sp = (sl & 0x23) | ((sl & 0x10) >> 2) | ((sl & 0x0C) << 1);
                int sc = (s & ~63) | sp;
                s16x4 pk;
                #pragma unroll
                for (int r = 0; r < 4; r++)
                    pk[r] = (short)f2bf(acc[mi][ni][r] + bv);
                *(s16x4*)&vT[((size_t)bb * HID + d) * S_LEN + sc] = pk;
            } else {
                #pragma unroll
                for (int r = 0; r < 4; r++)
                    qkv[(size_t)(row0 + r) * (2 * HID) + col] = f2bf((acc[mi][ni][r] + bv) * qsc);
            }
        }
    }
}

// BM=64 projection GEMM (fp32 out), BK=32 double-buffered.
__global__ __launch_bounds__(256)
void gemm64_kernel(const unsigned short* __restrict__ A, const unsigned short* __restrict__ Bt,
                   const float* __restrict__ bias, float* __restrict__ Cout,
                   int M, int N, int K) {
    __shared__ __align__(16) unsigned short As[2][64 * 32];
    __shared__ __align__(16) unsigned short Bs[2][128 * 32];

    const int tid  = threadIdx.x;
    const int lane = tid & 63;
    const int wv   = tid >> 6;
    const int wr   = wv >> 1, wc = wv & 1;
    const int m0   = blockIdx.y * 64, n0 = blockIdx.x * 128;

    const int lr = lane & 15;
    const int lg = lane >> 4;
    const int lk = lg * 8;

    const int srow = lane >> 2;
    const int scol = (lane & 3) * 8;

    const int arow = tid >> 2;
    const int acol = (tid & 3) * 8;

    f32x4 acc[2][4] = {};
    int cur = 0;

    gload_lds16(A + (size_t)(m0 + arow) * K + acol, &As[0][(arow & ~3) * 32]);
    #pragma unroll
    for (int l = 0; l < 2; l++) {
        const int r0 = wv * 32 + l * 16;
        gload_lds16(Bt + (size_t)(n0 + r0 + srow) * K + scol, &Bs[0][r0 * 32]);
    }

    for (int k0 = 0; k0 < K; k0 += 32) {
        __syncthreads();

        if (k0 + 32 < K) {
            gload_lds16(A + (size_t)(m0 + arow) * K + k0 + 32 + acol, &As[cur ^ 1][(arow & ~3) * 32]);
            #pragma unroll
            for (int l = 0; l < 2; l++) {
                const int r0 = wv * 32 + l * 16;
                gload_lds16(Bt + (size_t)(n0 + r0 + srow) * K + k0 + 32 + scol, &Bs[cur ^ 1][r0 * 32]);
            }
        }

        s16x8 af[2], bfr[4];
        #pragma unroll
        for (int mi = 0; mi < 2; mi++)
            af[mi] = *(const s16x8*)&As[cur][(wr * 32 + mi * 16 + lr) * 32 + lk];
        #pragma unroll
        for (int ni = 0; ni < 4; ni++)
            bfr[ni] = *(const s16x8*)&Bs[cur][(wc * 64 + ni * 16 + lr) * 32 + lk];
        #pragma unroll
        for (int mi = 0; mi < 2; mi++)
            #pragma unroll
            for (int ni = 0; ni < 4; ni++)
                acc[mi][ni] = __builtin_amdgcn_mfma_f32_16x16x32_bf16(af[mi], bfr[ni], acc[mi][ni], 0, 0, 0);
        cur ^= 1;
    }

    #pragma unroll
    for (int mi = 0; mi < 2; mi++) {
        #pragma unroll
        for (int ni = 0; ni < 4; ni++) {
            int col = n0 + wc * 64 + ni * 16 + lr;
            float bv = bias[col];
            #pragma unroll
            for (int r = 0; r < 4; r++) {
                int row = m0 + wr * 32 + mi * 16 + lg * 4 + r;
                Cout[(size_t)row * N + col] = acc[mi][ni][r] + bv;
            }
        }
    }
}

// One KV-tile of flash attention; DIAG instantiation carries the mask code,
// the (16/17-frequent) non-diag instantiation has none.
template<bool DIAG>
__device__ __forceinline__ void attn_tile(
    const unsigned short* __restrict__ Kt, const unsigned short* __restrict__ Vt,
    const s16x8 qf0, const s16x8 qf1, f32x4 (&o)[4], float& lsum,
    const int lr, const int lg, const int xo0, const int xo1, const int qlim)
{
    f32x4 sfT[4] = {};
    __builtin_amdgcn_s_setprio(1);
    #pragma unroll
    for (int ni = 0; ni < 4; ni++) {
        s16x8 kb = *(const s16x8*)&Kt[(ni * 16 + lr) * 64 + xo0];
        sfT[ni] = __builtin_amdgcn_mfma_f32_16x16x32_bf16(kb, qf0, sfT[ni], 0, 0, 0);
    }
    #pragma unroll
    for (int ni = 0; ni < 4; ni++) {
        s16x8 kb = *(const s16x8*)&Kt[(ni * 16 + lr) * 64 + xo1];
        sfT[ni] = __builtin_amdgcn_mfma_f32_16x16x32_bf16(kb, qf1, sfT[ni], 0, 0, 0);
    }
    __builtin_amdgcn_s_setprio(0);

    unsigned int own[4][2];
    #pragma unroll
    for (int ni = 0; ni < 4; ni++) {
        float pv[4];
        #pragma unroll
        for (int r = 0; r < 4; r++) {
            float s = sfT[ni][r];
            if (DIAG) {
                int kl = ni * 16 + lg * 4 + r;
                if (kl > qlim) s = -INFINITY;
            }
            pv[r] = exp2f(s);   // scale folded into Q; 2^c0 cancels in O/l
        }
        lsum += (pv[0] + pv[1]) + (pv[2] + pv[3]);
        own[ni][0] = cvtpk_bf16(pv[0], pv[1]);
        own[ni][1] = cvtpk_bf16(pv[2], pv[3]);
    }

    __builtin_amdgcn_s_setprio(1);
    #pragma unroll
    for (int kt = 0; kt < 2; kt++) {
        union { unsigned int u[4]; s16x8 v; } pa;
        pa.u[0] = own[2 * kt][0];
        pa.u[1] = own[2 * kt][1];
        pa.u[2] = own[2 * kt + 1][0];
        pa.u[3] = own[2 * kt + 1][1];
        const int xo = kt ? xo1 : xo0;
        #pragma unroll
        for (int dt = 0; dt < 4; dt++) {
            s16x8 vb = *(const s16x8*)&Vt[(dt * 16 + lr) * 64 + xo];
            o[dt] = __builtin_amdgcn_mfma_f32_16x16x32_bf16(vb, pa.v, o[dt], 0, 0, 0);
        }
    }
    __builtin_amdgcn_s_setprio(0);
}

// Flash attention, intra-block K-split: 512 threads = 2 wave-groups of 4;
// group 0 even KV tiles, group 1 odd (own dbuf K/V LDS); per-panel f32
// combine through LDS scratch; group 0 normalizes and writes.
// Triangle pairing {p,31-p}; XCD decode. Diag tile template-peeled.
__global__ __launch_bounds__(512)
void attn_kernel(const unsigned short* __restrict__ qkv, const unsigned short* __restrict__ vT,
                 unsigned short* __restrict__ out) {
    __shared__ __align__(16) unsigned short Ks[2][2][64 * 64];   // [grp][buf]
    __shared__ __align__(16) unsigned short Vs[2][2][64 * 64];

    const int tid  = threadIdx.x;
    const int lane = tid & 63;
    const int wv   = tid >> 6;
    const int grp  = wv >> 2;
    const int w    = wv & 3;

    const int wgid = blockIdx.x;
    const int xcd  = wgid & 7;
    const int slot = wgid >> 3;
    const int pp   = slot & 15;
    const int g    = (slot >> 4) * 8 + xcd;
    const int head = g & 15;
    const int b    = g >> 4;

    const size_t rowbase = (size_t)b * S_LEN;
    const int hoff = head * DKV;

    const int lr = lane & 15;
    const int lg = lane >> 4;
    const int lk = lg * 8;

    const int krow   = lane >> 3;
    const int kchunk = ((lane & 7) ^ krow) * 8;

    const int xo0 = (lg ^ (lr & 7)) * 8;
    const int xo1 = ((4 + lg) ^ (lr & 7)) * 8;
    const int qlim = w * 16 + lr;

    float* scratch = (float*)&Ks[0][0][0];

    #pragma unroll
    for (int panel = 0; panel < 2; panel++) {
        const int qb = (panel == 0) ? pp : (31 - pp);
        const int q0 = qb * 64;
        const int niter = (qb + 2) >> 1;

        s16x8 qf0, qf1;
        {
            const unsigned short* qp = qkv + (rowbase + q0 + w * 16 + lr) * (2 * HID) + hoff;
            qf0 = *(const s16x8*)(qp + lk);
            qf1 = *(const s16x8*)(qp + 32 + lk);
        }

        f32x4 o[4] = {};
        float lsum = 0.0f;
        int cur = 0;

        __syncthreads();
        if (grp <= qb) {
            const int j0 = grp * 64;
            #pragma unroll
            for (int l = 0; l < 2; l++) {
                const int r0 = (w * 2 + l) * 8;
                gload_lds16(qkv + (rowbase + j0 + r0 + krow) * (2 * HID) + HID + hoff + kchunk,
                            &Ks[grp][0][r0 * 64]);
                gload_lds16(vT + ((size_t)b * HID + hoff + r0 + krow) * S_LEN + j0 + kchunk,
                            &Vs[grp][0][r0 * 64]);
            }
        }

        for (int it = 0; it < niter; it++) {
            const int t = 2 * it + grp;
            __syncthreads();

            if (t + 2 <= qb) {
                const int jn = (t + 2) * 64;
                #pragma unroll
                for (int l = 0; l < 2; l++) {
                    const int r0 = (w * 2 + l) * 8;
                    gload_lds16(qkv + (rowbase + jn + r0 + krow) * (2 * HID) + HID + hoff + kchunk,
                                &Ks[grp][cur ^ 1][r0 * 64]);
                    gload_lds16(vT + ((size_t)b * HID + hoff + r0 + krow) * S_LEN + jn + kchunk,
                                &Vs[grp][cur ^ 1][r0 * 64]);
                }
            }

            if (t < qb) {
                attn_tile<false>(&Ks[grp][cur][0], &Vs[grp][cur][0], qf0, qf1, o, lsum,
                                 lr, lg, xo0, xo1, qlim);
            } else if (t == qb) {
                attn_tile<true>(&Ks[grp][cur][0], &Vs[grp][cur][0], qf0, qf1, o, lsum,
                                lr, lg, xo0, xo1, qlim);
            }
            cur ^= 1;
        }

        // intra-block combine: group 1 -> LDS scratch (f32), group 0 merges
        __syncthreads();
        const int sbase = (w * 64 + lane) * 17;
        if (grp == 1) {
            #pragma unroll
            for (int dt = 0; dt < 4; dt++)
                #pragma unroll
                for (int r = 0; r < 4; r++)
                    scratch[sbase + dt * 4 + r] = o[dt][r];
            scratch[sbase + 16] = lsum;
        }
        __syncthreads();
        if (grp == 0) {
            #pragma unroll
            for (int dt = 0; dt < 4; dt++)
                #pragma unroll
                for (int r = 0; r < 4; r++)
                    o[dt][r] += scratch[sbase + dt * 4 + r];
            lsum += scratch[sbase + 16];
            lsum += __shfl_xor(lsum, 16, 64);
            lsum += __shfl_xor(lsum, 32, 64);
            float invl = 1.0f / lsum;
            int qrow = q0 + w * 16 + lr;
            #pragma unroll
            for (int dt = 0; dt < 4; dt++) {
                s16x4 pk;
                #pragma unroll
                for (int r = 0; r < 4; r++) pk[r] = (short)f2bf(o[dt][r] * invl);
                *(s16x4*)&out[(rowbase + qrow) * HID + hoff + dt * 16 + lg * 4] = pk;
            }
        }
    }
}

extern "C" void kernel_launch(void* const* d_in, const int* in_sizes, int n_in,
                              void* d_out, int out_size, void* d_ws, size_t ws_size,
                              hipStream_t stream) {
    const float* x      = (const float*)d_in[0];
    const float* w_attn = (const float*)d_in[1];
    const float* b_attn = (const float*)d_in[2];
    const float* w_proj = (const float*)d_in[3];
    const float* b_proj = (const float*)d_in[4];
    float* out = (float*)d_out;

    char* ws = (char*)d_ws;
    unsigned short* qkv      = (unsigned short*)(ws);               // 16 MB [M][2H]
    unsigned short* waT      = (unsigned short*)(ws + 16777216);    // 6 MB
    unsigned short* wpT      = (unsigned short*)(ws + 23068672);    // 2 MB
    unsigned short* attn_out = (unsigned short*)(ws + 25165824);    // 8 MB (bf16)
    unsigned short* xb       = (unsigned short*)(ws + 33554432);    // 8 MB (bf16)
    unsigned short* vTr      = (unsigned short*)(ws + 41943040);    // 8 MB (bf16)

    const int M = BATCH * S_LEN;   // 4096

    prep_kernel<<<dim3(6144), 256, 0, stream>>>(x, xb, w_attn, waT, w_proj, wpT);

    gemm_qkv_kernel<<<dim3(3 * HID / 128, M / 128), 256, 0, stream>>>(
        xb, waT, b_attn, qkv, vTr, M, 3 * HID, HID);

    attn_kernel<<<dim3(512), 512, 0, stream>>>(qkv, vTr, attn_out);

    gemm64_kernel<<<dim3(HID / 128, M / 64), 256, 0, stream>>>(
        attn_out, wpT, b_proj, out, M, HID, HID);
}

// Round 20
// 109.322 us; speedup vs baseline: 1.0017x; 1.0017x over previous
//
#include <hip/hip_runtime.h>

#define BATCH 2
#define S_LEN 2048
#define NHEADS 16
#define DKV 64
#define HID 1024

typedef __attribute__((ext_vector_type(8))) short s16x8;
typedef __attribute__((ext_vector_type(4))) short s16x4;
typedef __attribute__((ext_vector_type(4))) float f32x4;

__device__ inline unsigned short f2bf(float f) {
    union { float f; unsigned int u; } v; v.f = f;
    unsigned int r = v.u + 0x7fffu + ((v.u >> 16) & 1u);
    return (unsigned short)(r >> 16);
}

__device__ inline s16x8 pack8(float4 a, float4 b) {
    s16x8 r;
    r[0] = (short)f2bf(a.x); r[1] = (short)f2bf(a.y);
    r[2] = (short)f2bf(a.z); r[3] = (short)f2bf(a.w);
    r[4] = (short)f2bf(b.x); r[5] = (short)f2bf(b.y);
    r[6] = (short)f2bf(b.z); r[7] = (short)f2bf(b.w);
    return r;
}

__device__ inline void gload_lds16(const void* g, void* l) {
    __builtin_amdgcn_global_load_lds(
        (const __attribute__((address_space(1))) void*)g,
        (__attribute__((address_space(3))) void*)l, 16, 0, 0);
}

__device__ inline unsigned int cvtpk_bf16(float lo, float hi) {
    unsigned int d;
    asm("v_cvt_pk_bf16_f32 %0, %1, %2" : "=v"(d) : "v"(lo), "v"(hi));
    return d;
}

// Merged prep: [0,2048) x f32->bf16; [2048,5120) w_attn transpose;
// [5120,6144) w_proj transpose.
__global__ __launch_bounds__(256)
void prep_kernel(const float* __restrict__ x, unsigned short* __restrict__ xb,
                 const float* __restrict__ w_attn, unsigned short* __restrict__ waT,
                 const float* __restrict__ w_proj, unsigned short* __restrict__ wpT) {
    __shared__ float tile[32][33];
    const int blk = blockIdx.x;
    const int tid = threadIdx.x;

    if (blk < 2048) {
        int i = blk * 256 + tid;
        const float4* p = (const float4*)(x + (size_t)i * 8);
        float4 a = p[0], b = p[1];
        *(s16x8*)(xb + (size_t)i * 8) = pack8(a, b);
        return;
    }

    const float* in;
    unsigned short* outp;
    int n0, k0, N;
    if (blk < 5120) {
        int idx = blk - 2048;
        N = 3 * HID;
        n0 = (idx % 96) * 32; k0 = (idx / 96) * 32;
        in = w_attn; outp = waT;
    } else {
        int idx = blk - 5120;
        N = HID;
        n0 = (idx % 32) * 32; k0 = (idx / 32) * 32;
        in = w_proj; outp = wpT;
    }
    const int tx = tid & 31, ty = tid >> 5;
    for (int i = ty; i < 32; i += 8)
        tile[i][tx] = in[(size_t)(k0 + i) * N + n0 + tx];
    __syncthreads();
    // widened write: 4 bf16 (b64) per thread
    {
        const int n  = tid >> 3;          // 0..31
        const int kc = (tid & 7) * 4;     // 0..28
        s16x4 pk;
        #pragma unroll
        for (int j = 0; j < 4; j++) pk[j] = (short)f2bf(tile[kc + j][n]);
        *(s16x4*)&outp[(size_t)(n0 + n) * HID + k0 + kc] = pk;
    }
}

// QKV GEMM: BK=32, linear LDS, double-buffered staging, 2D grid (n-fastest).
// Q columns pre-scaled by 0.125*log2e (softmax scale folded into Q).
// Q/K columns -> qkv[M][2H]; V columns -> vT[b][d][s'] key-permuted
// (s' = [s5,s3,s2,s4,s1,s0]) for the zero-shuffle PV in attn.
__global__ __launch_bounds__(256)
void gemm_qkv_kernel(const unsigned short* __restrict__ A, const unsigned short* __restrict__ Bt,
                     const float* __restrict__ bias, unsigned short* __restrict__ qkv,
                     unsigned short* __restrict__ vT, int M, int N, int K) {
    __shared__ __align__(16) unsigned short As[2][128 * 32];
    __shared__ __align__(16) unsigned short Bs[2][128 * 32];

    const int tid  = threadIdx.x;
    const int lane = tid & 63;
    const int wv   = tid >> 6;
    const int wr   = wv >> 1, wc = wv & 1;
    const int m0   = blockIdx.y * 128, n0 = blockIdx.x * 128;

    const int lr = lane & 15;
    const int lg = lane >> 4;
    const int lk = lg * 8;

    const int srow = lane >> 2;
    const int scol = (lane & 3) * 8;

    f32x4 acc[4][4] = {};
    int cur = 0;

    #pragma unroll
    for (int l = 0; l < 2; l++) {
        const int r0 = wv * 32 + l * 16;
        gload_lds16(A  + (size_t)(m0 + r0 + srow) * K + scol, &As[0][r0 * 32]);
        gload_lds16(Bt + (size_t)(n0 + r0 + srow) * K + scol, &Bs[0][r0 * 32]);
    }

    for (int k0 = 0; k0 < K; k0 += 32) {
        __syncthreads();

        if (k0 + 32 < K) {
            #pragma unroll
            for (int l = 0; l < 2; l++) {
                const int r0 = wv * 32 + l * 16;
                gload_lds16(A  + (size_t)(m0 + r0 + srow) * K + k0 + 32 + scol, &As[cur ^ 1][r0 * 32]);
                gload_lds16(Bt + (size_t)(n0 + r0 + srow) * K + k0 + 32 + scol, &Bs[cur ^ 1][r0 * 32]);
            }
        }

        s16x8 af[4], bfr[4];
        #pragma unroll
        for (int mi = 0; mi < 4; mi++)
            af[mi] = *(const s16x8*)&As[cur][(wr * 64 + mi * 16 + lr) * 32 + lk];
        #pragma unroll
        for (int ni = 0; ni < 4; ni++)
            bfr[ni] = *(const s16x8*)&Bs[cur][(wc * 64 + ni * 16 + lr) * 32 + lk];
        #pragma unroll
        for (int mi = 0; mi < 4; mi++)
            #pragma unroll
            for (int ni = 0; ni < 4; ni++)
                acc[mi][ni] = __builtin_amdgcn_mfma_f32_16x16x32_bf16(af[mi], bfr[ni], acc[mi][ni], 0, 0, 0);
        cur ^= 1;
    }

    const bool isV = (n0 >= 2 * HID);
    const float qsc = (n0 < HID) ? 0.18033688f : 1.0f;   // fold softmax scale into Q
    #pragma unroll
    for (int mi = 0; mi < 4; mi++) {
        #pragma unroll
        for (int ni = 0; ni < 4; ni++) {
            int col = n0 + wc * 64 + ni * 16 + lr;
            float bv = bias[col];
            int row0 = m0 + wr * 64 + mi * 16 + lg * 4;
            if (isV) {
                int d = col - 2 * HID;
                int bb = row0 >> 11;
                int s = row0 & (S_LEN - 1);
                int sl = s & 63;
                int sp = (sl & 0x23) | ((sl & 0x10) >> 2) | ((sl & 0x0C) << 1);
                int sc = (s & ~63) | sp;
                s16x4 pk;
                #pragma unroll
                for (int r = 0; r < 4; r++)
                    pk[r] = (short)f2bf(acc[mi][ni][r] + bv);
                *(s16x4*)&vT[((size_t)bb * HID + d) * S_LEN + sc] = pk;
            } else {
                #pragma unroll
                for (int r = 0; r < 4; r++)
                    qkv[(size_t)(row0 + r) * (2 * HID) + col] = f2bf((acc[mi][ni][r] + bv) * qsc);
            }
        }
    }
}

// BM=64 projection GEMM (fp32 out), BK=32 double-buffered.
__global__ __launch_bounds__(256)
void gemm64_kernel(const unsigned short* __restrict__ A, const unsigned short* __restrict__ Bt,
                   const float* __restrict__ bias, float* __restrict__ Cout,
                   int M, int N, int K) {
    __shared__ __align__(16) unsigned short As[2][64 * 32];
    __shared__ __align__(16) unsigned short Bs[2][128 * 32];

    const int tid  = threadIdx.x;
    const int lane = tid & 63;
    const int wv   = tid >> 6;
    const int wr   = wv >> 1, wc = wv & 1;
    const int m0   = blockIdx.y * 64, n0 = blockIdx.x * 128;

    const int lr = lane & 15;
    const int lg = lane >> 4;
    const int lk = lg * 8;

    const int srow = lane >> 2;
    const int scol = (lane & 3) * 8;

    const int arow = tid >> 2;
    const int acol = (tid & 3) * 8;

    f32x4 acc[2][4] = {};
    int cur = 0;

    gload_lds16(A + (size_t)(m0 + arow) * K + acol, &As[0][(arow & ~3) * 32]);
    #pragma unroll
    for (int l = 0; l < 2; l++) {
        const int r0 = wv * 32 + l * 16;
        gload_lds16(Bt + (size_t)(n0 + r0 + srow) * K + scol, &Bs[0][r0 * 32]);
    }

    for (int k0 = 0; k0 < K; k0 += 32) {
        __syncthreads();

        if (k0 + 32 < K) {
            gload_lds16(A + (size_t)(m0 + arow) * K + k0 + 32 + acol, &As[cur ^ 1][(arow & ~3) * 32]);
            #pragma unroll
            for (int l = 0; l < 2; l++) {
                const int r0 = wv * 32 + l * 16;
                gload_lds16(Bt + (size_t)(n0 + r0 + srow) * K + k0 + 32 + scol, &Bs[cur ^ 1][r0 * 32]);
            }
        }

        s16x8 af[2], bfr[4];
        #pragma unroll
        for (int mi = 0; mi < 2; mi++)
            af[mi] = *(const s16x8*)&As[cur][(wr * 32 + mi * 16 + lr) * 32 + lk];
        #pragma unroll
        for (int ni = 0; ni < 4; ni++)
            bfr[ni] = *(const s16x8*)&Bs[cur][(wc * 64 + ni * 16 + lr) * 32 + lk];
        #pragma unroll
        for (int mi = 0; mi < 2; mi++)
            #pragma unroll
            for (int ni = 0; ni < 4; ni++)
                acc[mi][ni] = __builtin_amdgcn_mfma_f32_16x16x32_bf16(af[mi], bfr[ni], acc[mi][ni], 0, 0, 0);
        cur ^= 1;
    }

    #pragma unroll
    for (int mi = 0; mi < 2; mi++) {
        #pragma unroll
        for (int ni = 0; ni < 4; ni++) {
            int col = n0 + wc * 64 + ni * 16 + lr;
            float bv = bias[col];
            #pragma unroll
            for (int r = 0; r < 4; r++) {
                int row = m0 + wr * 32 + mi * 16 + lg * 4 + r;
                Cout[(size_t)row * N + col] = acc[mi][ni][r] + bv;
            }
        }
    }
}

// One KV-tile of flash attention; DIAG instantiation carries the mask code,
// the (16/17-frequent) non-diag instantiation has none.
template<bool DIAG>
__device__ __forceinline__ void attn_tile(
    const unsigned short* __restrict__ Kt, const unsigned short* __restrict__ Vt,
    const s16x8 qf0, const s16x8 qf1, f32x4 (&o)[4], float& lsum,
    const int lr, const int lg, const int xo0, const int xo1, const int qlim)
{
    f32x4 sfT[4] = {};
    __builtin_amdgcn_s_setprio(1);
    #pragma unroll
    for (int ni = 0; ni < 4; ni++) {
        s16x8 kb = *(const s16x8*)&Kt[(ni * 16 + lr) * 64 + xo0];
        sfT[ni] = __builtin_amdgcn_mfma_f32_16x16x32_bf16(kb, qf0, sfT[ni], 0, 0, 0);
    }
    #pragma unroll
    for (int ni = 0; ni < 4; ni++) {
        s16x8 kb = *(const s16x8*)&Kt[(ni * 16 + lr) * 64 + xo1];
        sfT[ni] = __builtin_amdgcn_mfma_f32_16x16x32_bf16(kb, qf1, sfT[ni], 0, 0, 0);
    }
    __builtin_amdgcn_s_setprio(0);

    unsigned int own[4][2];
    #pragma unroll
    for (int ni = 0; ni < 4; ni++) {
        float pv[4];
        #pragma unroll
        for (int r = 0; r < 4; r++) {
            float s = sfT[ni][r];
            if (DIAG) {
                int kl = ni * 16 + lg * 4 + r;
                if (kl > qlim) s = -INFINITY;
            }
            pv[r] = exp2f(s);   // scale folded into Q; 2^c0 cancels in O/l
        }
        lsum += (pv[0] + pv[1]) + (pv[2] + pv[3]);
        own[ni][0] = cvtpk_bf16(pv[0], pv[1]);
        own[ni][1] = cvtpk_bf16(pv[2], pv[3]);
    }

    __builtin_amdgcn_s_setprio(1);
    #pragma unroll
    for (int kt = 0; kt < 2; kt++) {
        union { unsigned int u[4]; s16x8 v; } pa;
        pa.u[0] = own[2 * kt][0];
        pa.u[1] = own[2 * kt][1];
        pa.u[2] = own[2 * kt + 1][0];
        pa.u[3] = own[2 * kt + 1][1];
        const int xo = kt ? xo1 : xo0;
        #pragma unroll
        for (int dt = 0; dt < 4; dt++) {
            s16x8 vb = *(const s16x8*)&Vt[(dt * 16 + lr) * 64 + xo];
            o[dt] = __builtin_amdgcn_mfma_f32_16x16x32_bf16(vb, pa.v, o[dt], 0, 0, 0);
        }
    }
    __builtin_amdgcn_s_setprio(0);
}

// Flash attention, intra-block K-split: 512 threads = 2 wave-groups of 4;
// group 0 even KV tiles, group 1 odd (own dbuf K/V LDS); per-panel f32
// combine through LDS scratch; group 0 normalizes and writes.
// Triangle pairing {p,31-p}; XCD decode. Diag tile template-peeled.
__global__ __launch_bounds__(512)
void attn_kernel(const unsigned short* __restrict__ qkv, const unsigned short* __restrict__ vT,
                 unsigned short* __restrict__ out) {
    __shared__ __align__(16) unsigned short Ks[2][2][64 * 64];   // [grp][buf]
    __shared__ __align__(16) unsigned short Vs[2][2][64 * 64];

    const int tid  = threadIdx.x;
    const int lane = tid & 63;
    const int wv   = tid >> 6;
    const int grp  = wv >> 2;
    const int w    = wv & 3;

    const int wgid = blockIdx.x;
    const int xcd  = wgid & 7;
    const int slot = wgid >> 3;
    const int pp   = slot & 15;
    const int g    = (slot >> 4) * 8 + xcd;
    const int head = g & 15;
    const int b    = g >> 4;

    const size_t rowbase = (size_t)b * S_LEN;
    const int hoff = head * DKV;

    const int lr = lane & 15;
    const int lg = lane >> 4;
    const int lk = lg * 8;

    const int krow   = lane >> 3;
    const int kchunk = ((lane & 7) ^ krow) * 8;

    const int xo0 = (lg ^ (lr & 7)) * 8;
    const int xo1 = ((4 + lg) ^ (lr & 7)) * 8;
    const int qlim = w * 16 + lr;

    float* scratch = (float*)&Ks[0][0][0];

    #pragma unroll
    for (int panel = 0; panel < 2; panel++) {
        const int qb = (panel == 0) ? pp : (31 - pp);
        const int q0 = qb * 64;
        const int niter = (qb + 2) >> 1;

        s16x8 qf0, qf1;
        {
            const unsigned short* qp = qkv + (rowbase + q0 + w * 16 + lr) * (2 * HID) + hoff;
            qf0 = *(const s16x8*)(qp + lk);
            qf1 = *(const s16x8*)(qp + 32 + lk);
        }

        f32x4 o[4] = {};
        float lsum = 0.0f;
        int cur = 0;

        __syncthreads();
        if (grp <= qb) {
            const int j0 = grp * 64;
            #pragma unroll
            for (int l = 0; l < 2; l++) {
                const int r0 = (w * 2 + l) * 8;
                gload_lds16(qkv + (rowbase + j0 + r0 + krow) * (2 * HID) + HID + hoff + kchunk,
                            &Ks[grp][0][r0 * 64]);
                gload_lds16(vT + ((size_t)b * HID + hoff + r0 + krow) * S_LEN + j0 + kchunk,
                            &Vs[grp][0][r0 * 64]);
            }
        }

        for (int it = 0; it < niter; it++) {
            const int t = 2 * it + grp;
            __syncthreads();

            if (t + 2 <= qb) {
                const int jn = (t + 2) * 64;
                #pragma unroll
                for (int l = 0; l < 2; l++) {
                    const int r0 = (w * 2 + l) * 8;
                    gload_lds16(qkv + (rowbase + jn + r0 + krow) * (2 * HID) + HID + hoff + kchunk,
                                &Ks[grp][cur ^ 1][r0 * 64]);
                    gload_lds16(vT + ((size_t)b * HID + hoff + r0 + krow) * S_LEN + jn + kchunk,
                                &Vs[grp][cur ^ 1][r0 * 64]);
                }
            }

            if (t < qb) {
                attn_tile<false>(&Ks[grp][cur][0], &Vs[grp][cur][0], qf0, qf1, o, lsum,
                                 lr, lg, xo0, xo1, qlim);
            } else if (t == qb) {
                attn_tile<true>(&Ks[grp][cur][0], &Vs[grp][cur][0], qf0, qf1, o, lsum,
                                lr, lg, xo0, xo1, qlim);
            }
            cur ^= 1;
        }

        // intra-block combine: group 1 -> LDS scratch (f32), group 0 merges
        __syncthreads();
        const int sbase = (w * 64 + lane) * 17;
        if (grp == 1) {
            #pragma unroll
            for (int dt = 0; dt < 4; dt++)
                #pragma unroll
                for (int r = 0; r < 4; r++)
                    scratch[sbase + dt * 4 + r] = o[dt][r];
            scratch[sbase + 16] = lsum;
        }
        __syncthreads();
        if (grp == 0) {
            #pragma unroll
            for (int dt = 0; dt < 4; dt++)
                #pragma unroll
                for (int r = 0; r < 4; r++)
                    o[dt][r] += scratch[sbase + dt * 4 + r];
            lsum += scratch[sbase + 16];
            lsum += __shfl_xor(lsum, 16, 64);
            lsum += __shfl_xor(lsum, 32, 64);
            float invl = 1.0f / lsum;
            int qrow = q0 + w * 16 + lr;
            #pragma unroll
            for (int dt = 0; dt < 4; dt++) {
                s16x4 pk;
                #pragma unroll
                for (int r = 0; r < 4; r++) pk[r] = (short)f2bf(o[dt][r] * invl);
                *(s16x4*)&out[(rowbase + qrow) * HID + hoff + dt * 16 + lg * 4] = pk;
            }
        }
    }
}

extern "C" void kernel_launch(void* const* d_in, const int* in_sizes, int n_in,
                              void* d_out, int out_size, void* d_ws, size_t ws_size,
                              hipStream_t stream) {
    const float* x      = (const float*)d_in[0];
    const float* w_attn = (const float*)d_in[1];
    const float* b_attn = (const float*)d_in[2];
    const float* w_proj = (const float*)d_in[3];
    const float* b_proj = (const float*)d_in[4];
    float* out = (float*)d_out;

    char* ws = (char*)d_ws;
    unsigned short* qkv      = (unsigned short*)(ws);               // 16 MB [M][2H]
    unsigned short* waT      = (unsigned short*)(ws + 16777216);    // 6 MB
    unsigned short* wpT      = (unsigned short*)(ws + 23068672);    // 2 MB
    unsigned short* attn_out = (unsigned short*)(ws + 25165824);    // 8 MB (bf16)
    unsigned short* xb       = (unsigned short*)(ws + 33554432);    // 8 MB (bf16)
    unsigned short* vTr      = (unsigned short*)(ws + 41943040);    // 8 MB (bf16)

    const int M = BATCH * S_LEN;   // 4096

    prep_kernel<<<dim3(6144), 256, 0, stream>>>(x, xb, w_attn, waT, w_proj, wpT);

    gemm_qkv_kernel<<<dim3(3 * HID / 128, M / 128), 256, 0, stream>>>(
        xb, waT, b_attn, qkv, vTr, M, 3 * HID, HID);

    attn_kernel<<<dim3(512), 512, 0, stream>>>(qkv, vTr, attn_out);

    gemm64_kernel<<<dim3(HID / 128, M / 64), 256, 0, stream>>>(
        attn_out, wpT, b_proj, out, M, HID, HID);
}

// Round 21
// 105.311 us; speedup vs baseline: 1.0398x; 1.0381x over previous
//
#include <hip/hip_runtime.h>

#define BATCH 2
#define S_LEN 2048
#define NHEADS 16
#define DKV 64
#define HID 1024

typedef __attribute__((ext_vector_type(8))) short s16x8;
typedef __attribute__((ext_vector_type(4))) short s16x4;
typedef __attribute__((ext_vector_type(4))) float f32x4;

__device__ inline unsigned short f2bf(float f) {
    union { float f; unsigned int u; } v; v.f = f;
    unsigned int r = v.u + 0x7fffu + ((v.u >> 16) & 1u);
    return (unsigned short)(r >> 16);
}

__device__ inline s16x8 pack8(float4 a, float4 b) {
    s16x8 r;
    r[0] = (short)f2bf(a.x); r[1] = (short)f2bf(a.y);
    r[2] = (short)f2bf(a.z); r[3] = (short)f2bf(a.w);
    r[4] = (short)f2bf(b.x); r[5] = (short)f2bf(b.y);
    r[6] = (short)f2bf(b.z); r[7] = (short)f2bf(b.w);
    return r;
}

__device__ inline void gload_lds16(const void* g, void* l) {
    __builtin_amdgcn_global_load_lds(
        (const __attribute__((address_space(1))) void*)g,
        (__attribute__((address_space(3))) void*)l, 16, 0, 0);
}

__device__ inline unsigned int cvtpk_bf16(float lo, float hi) {
    unsigned int d;
    asm("v_cvt_pk_bf16_f32 %0, %1, %2" : "=v"(d) : "v"(lo), "v"(hi));
    return d;
}

// Merged prep: [0,2048) x f32->bf16; [2048,5120) w_attn transpose;
// [5120,6144) w_proj transpose.
__global__ __launch_bounds__(256)
void prep_kernel(const float* __restrict__ x, unsigned short* __restrict__ xb,
                 const float* __restrict__ w_attn, unsigned short* __restrict__ waT,
                 const float* __restrict__ w_proj, unsigned short* __restrict__ wpT) {
    __shared__ float tile[32][33];
    const int blk = blockIdx.x;
    const int tid = threadIdx.x;

    if (blk < 2048) {
        int i = blk * 256 + tid;
        const float4* p = (const float4*)(x + (size_t)i * 8);
        float4 a = p[0], b = p[1];
        *(s16x8*)(xb + (size_t)i * 8) = pack8(a, b);
        return;
    }

    const float* in;
    unsigned short* outp;
    int n0, k0, N;
    if (blk < 5120) {
        int idx = blk - 2048;
        N = 3 * HID;
        n0 = (idx % 96) * 32; k0 = (idx / 96) * 32;
        in = w_attn; outp = waT;
    } else {
        int idx = blk - 5120;
        N = HID;
        n0 = (idx % 32) * 32; k0 = (idx / 32) * 32;
        in = w_proj; outp = wpT;
    }
    const int tx = tid & 31, ty = tid >> 5;
    for (int i = ty; i < 32; i += 8)
        tile[i][tx] = in[(size_t)(k0 + i) * N + n0 + tx];
    __syncthreads();
    {
        const int n  = tid >> 3;
        const int kc = (tid & 7) * 4;
        s16x4 pk;
        #pragma unroll
        for (int j = 0; j < 4; j++) pk[j] = (short)f2bf(tile[kc + j][n]);
        *(s16x4*)&outp[(size_t)(n0 + n) * HID + k0 + kc] = pk;
    }
}

// QKV GEMM: BK=32, linear LDS, double-buffered staging, 2D grid (n-fastest).
// Q columns pre-scaled by 0.125*log2e (softmax scale folded into Q).
// Q/K columns -> qkv[M][2H]; V columns -> vT[b][d][s'] key-permuted
// (s' = [s5,s3,s2,s4,s1,s0]) for the zero-shuffle PV in attn.
__global__ __launch_bounds__(256)
void gemm_qkv_kernel(const unsigned short* __restrict__ A, const unsigned short* __restrict__ Bt,
                     const float* __restrict__ bias, unsigned short* __restrict__ qkv,
                     unsigned short* __restrict__ vT, int M, int N, int K) {
    __shared__ __align__(16) unsigned short As[2][128 * 32];
    __shared__ __align__(16) unsigned short Bs[2][128 * 32];

    const int tid  = threadIdx.x;
    const int lane = tid & 63;
    const int wv   = tid >> 6;
    const int wr   = wv >> 1, wc = wv & 1;
    const int m0   = blockIdx.y * 128, n0 = blockIdx.x * 128;

    const int lr = lane & 15;
    const int lg = lane >> 4;
    const int lk = lg * 8;

    const int srow = lane >> 2;
    const int scol = (lane & 3) * 8;

    f32x4 acc[4][4] = {};
    int cur = 0;

    #pragma unroll
    for (int l = 0; l < 2; l++) {
        const int r0 = wv * 32 + l * 16;
        gload_lds16(A  + (size_t)(m0 + r0 + srow) * K + scol, &As[0][r0 * 32]);
        gload_lds16(Bt + (size_t)(n0 + r0 + srow) * K + scol, &Bs[0][r0 * 32]);
    }

    for (int k0 = 0; k0 < K; k0 += 32) {
        __syncthreads();

        if (k0 + 32 < K) {
            #pragma unroll
            for (int l = 0; l < 2; l++) {
                const int r0 = wv * 32 + l * 16;
                gload_lds16(A  + (size_t)(m0 + r0 + srow) * K + k0 + 32 + scol, &As[cur ^ 1][r0 * 32]);
                gload_lds16(Bt + (size_t)(n0 + r0 + srow) * K + k0 + 32 + scol, &Bs[cur ^ 1][r0 * 32]);
            }
        }

        s16x8 af[4], bfr[4];
        #pragma unroll
        for (int mi = 0; mi < 4; mi++)
            af[mi] = *(const s16x8*)&As[cur][(wr * 64 + mi * 16 + lr) * 32 + lk];
        #pragma unroll
        for (int ni = 0; ni < 4; ni++)
            bfr[ni] = *(const s16x8*)&Bs[cur][(wc * 64 + ni * 16 + lr) * 32 + lk];
        #pragma unroll
        for (int mi = 0; mi < 4; mi++)
            #pragma unroll
            for (int ni = 0; ni < 4; ni++)
                acc[mi][ni] = __builtin_amdgcn_mfma_f32_16x16x32_bf16(af[mi], bfr[ni], acc[mi][ni], 0, 0, 0);
        cur ^= 1;
    }

    const bool isV = (n0 >= 2 * HID);
    const float qsc = (n0 < HID) ? 0.18033688f : 1.0f;
    #pragma unroll
    for (int mi = 0; mi < 4; mi++) {
        #pragma unroll
        for (int ni = 0; ni < 4; ni++) {
            int col = n0 + wc * 64 + ni * 16 + lr;
            float bv = bias[col];
            int row0 = m0 + wr * 64 + mi * 16 + lg * 4;
            if (isV) {
                int d = col - 2 * HID;
                int bb = row0 >> 11;
                int s = row0 & (S_LEN - 1);
                int sl = s & 63;
                int sp = (sl & 0x23) | ((sl & 0x10) >> 2) | ((sl & 0x0C) << 1);
                int sc = (s & ~63) | sp;
                s16x4 pk;
                #pragma unroll
                for (int r = 0; r < 4; r++)
                    pk[r] = (short)f2bf(acc[mi][ni][r] + bv);
                *(s16x4*)&vT[((size_t)bb * HID + d) * S_LEN + sc] = pk;
            } else {
                #pragma unroll
                for (int r = 0; r < 4; r++)
                    qkv[(size_t)(row0 + r) * (2 * HID) + col] = f2bf((acc[mi][ni][r] + bv) * qsc);
            }
        }
    }
}

// BM=64 projection GEMM (fp32 out), BK=32 double-buffered.
__global__ __launch_bounds__(256)
void gemm64_kernel(const unsigned short* __restrict__ A, const unsigned short* __restrict__ Bt,
                   const float* __restrict__ bias, float* __restrict__ Cout,
                   int M, int N, int K) {
    __shared__ __align__(16) unsigned short As[2][64 * 32];
    __shared__ __align__(16) unsigned short Bs[2][128 * 32];

    const int tid  = threadIdx.x;
    const int lane = tid & 63;
    const int wv   = tid >> 6;
    const int wr   = wv >> 1, wc = wv & 1;
    const int m0   = blockIdx.y * 64, n0 = blockIdx.x * 128;

    const int lr = lane & 15;
    const int lg = lane >> 4;
    const int lk = lg * 8;

    const int srow = lane >> 2;
    const int scol = (lane & 3) * 8;

    const int arow = tid >> 2;
    const int acol = (tid & 3) * 8;

    f32x4 acc[2][4] = {};
    int cur = 0;

    gload_lds16(A + (size_t)(m0 + arow) * K + acol, &As[0][(arow & ~3) * 32]);
    #pragma unroll
    for (int l = 0; l < 2; l++) {
        const int r0 = wv * 32 + l * 16;
        gload_lds16(Bt + (size_t)(n0 + r0 + srow) * K + scol, &Bs[0][r0 * 32]);
    }

    for (int k0 = 0; k0 < K; k0 += 32) {
        __syncthreads();

        if (k0 + 32 < K) {
            gload_lds16(A + (size_t)(m0 + arow) * K + k0 + 32 + acol, &As[cur ^ 1][(arow & ~3) * 32]);
            #pragma unroll
            for (int l = 0; l < 2; l++) {
                const int r0 = wv * 32 + l * 16;
                gload_lds16(Bt + (size_t)(n0 + r0 + srow) * K + k0 + 32 + scol, &Bs[cur ^ 1][r0 * 32]);
            }
        }

        s16x8 af[2], bfr[4];
        #pragma unroll
        for (int mi = 0; mi < 2; mi++)
            af[mi] = *(const s16x8*)&As[cur][(wr * 32 + mi * 16 + lr) * 32 + lk];
        #pragma unroll
        for (int ni = 0; ni < 4; ni++)
            bfr[ni] = *(const s16x8*)&Bs[cur][(wc * 64 + ni * 16 + lr) * 32 + lk];
        #pragma unroll
        for (int mi = 0; mi < 2; mi++)
            #pragma unroll
            for (int ni = 0; ni < 4; ni++)
                acc[mi][ni] = __builtin_amdgcn_mfma_f32_16x16x32_bf16(af[mi], bfr[ni], acc[mi][ni], 0, 0, 0);
        cur ^= 1;
    }

    #pragma unroll
    for (int mi = 0; mi < 2; mi++) {
        #pragma unroll
        for (int ni = 0; ni < 4; ni++) {
            int col = n0 + wc * 64 + ni * 16 + lr;
            float bv = bias[col];
            #pragma unroll
            for (int r = 0; r < 4; r++) {
                int row = m0 + wr * 32 + mi * 16 + lg * 4 + r;
                Cout[(size_t)row * N + col] = acc[mi][ni][r] + bv;
            }
        }
    }
}

// One KV-tile, 32 q-rows per wave (two 16-q halves A/B sharing kb/vb reads).
// DIAG instantiation carries mask code (qlim pre-offset by grp*64).
template<bool DIAG>
__device__ __forceinline__ void attn_tile32(
    const unsigned short* __restrict__ Kt, const unsigned short* __restrict__ Vt,
    const s16x8 qf0, const s16x8 qf1, const s16x8 qg0, const s16x8 qg1,
    f32x4 (&oA)[4], f32x4 (&oB)[4], float& lsumA, float& lsumB,
    const int lr, const int lg, const int xo0, const int xo1,
    const int qlimA, const int qlimB)
{
    f32x4 sA[4] = {}, sB[4] = {};
    __builtin_amdgcn_s_setprio(1);
    #pragma unroll
    for (int ni = 0; ni < 4; ni++) {
        s16x8 kb = *(const s16x8*)&Kt[(ni * 16 + lr) * 64 + xo0];
        sA[ni] = __builtin_amdgcn_mfma_f32_16x16x32_bf16(kb, qf0, sA[ni], 0, 0, 0);
        sB[ni] = __builtin_amdgcn_mfma_f32_16x16x32_bf16(kb, qg0, sB[ni], 0, 0, 0);
    }
    #pragma unroll
    for (int ni = 0; ni < 4; ni++) {
        s16x8 kb = *(const s16x8*)&Kt[(ni * 16 + lr) * 64 + xo1];
        sA[ni] = __builtin_amdgcn_mfma_f32_16x16x32_bf16(kb, qf1, sA[ni], 0, 0, 0);
        sB[ni] = __builtin_amdgcn_mfma_f32_16x16x32_bf16(kb, qg1, sB[ni], 0, 0, 0);
    }
    __builtin_amdgcn_s_setprio(0);

    unsigned int ownA[4][2], ownB[4][2];
    #pragma unroll
    for (int ni = 0; ni < 4; ni++) {
        float pvA[4], pvB[4];
        #pragma unroll
        for (int r = 0; r < 4; r++) {
            float sa = sA[ni][r];
            float sb = sB[ni][r];
            if (DIAG) {
                int kl = ni * 16 + lg * 4 + r;
                if (kl > qlimA) sa = -INFINITY;
                if (kl > qlimB) sb = -INFINITY;
            }
            pvA[r] = exp2f(sa);
            pvB[r] = exp2f(sb);
        }
        lsumA += (pvA[0] + pvA[1]) + (pvA[2] + pvA[3]);
        lsumB += (pvB[0] + pvB[1]) + (pvB[2] + pvB[3]);
        ownA[ni][0] = cvtpk_bf16(pvA[0], pvA[1]);
        ownA[ni][1] = cvtpk_bf16(pvA[2], pvA[3]);
        ownB[ni][0] = cvtpk_bf16(pvB[0], pvB[1]);
        ownB[ni][1] = cvtpk_bf16(pvB[2], pvB[3]);
    }

    __builtin_amdgcn_s_setprio(1);
    #pragma unroll
    for (int kt = 0; kt < 2; kt++) {
        union { unsigned int u[4]; s16x8 v; } paA, paB;
        paA.u[0] = ownA[2 * kt][0]; paA.u[1] = ownA[2 * kt][1];
        paA.u[2] = ownA[2 * kt + 1][0]; paA.u[3] = ownA[2 * kt + 1][1];
        paB.u[0] = ownB[2 * kt][0]; paB.u[1] = ownB[2 * kt][1];
        paB.u[2] = ownB[2 * kt + 1][0]; paB.u[3] = ownB[2 * kt + 1][1];
        const int xo = kt ? xo1 : xo0;
        #pragma unroll
        for (int dt = 0; dt < 4; dt++) {
            s16x8 vb = *(const s16x8*)&Vt[(dt * 16 + lr) * 64 + xo];
            oA[dt] = __builtin_amdgcn_mfma_f32_16x16x32_bf16(vb, paA.v, oA[dt], 0, 0, 0);
            oB[dt] = __builtin_amdgcn_mfma_f32_16x16x32_bf16(vb, paB.v, oB[dt], 0, 0, 0);
        }
    }
    __builtin_amdgcn_s_setprio(0);
}

// Flash attention, 32 q-rows/wave: 512 threads = 4 q-waves x 2 K-parity
// groups. Block = 128-row panel pair {p, 15-p} -> uniform 17 iterations.
// 256 blocks = 1/CU, 2 waves/SIMD, high per-wave ILP (m214 shape).
// Intra-block f32 combine via LDS scratch; zero-shuffle PV; XCD grouping.
__global__ __launch_bounds__(512, 2)
void attn_kernel(const unsigned short* __restrict__ qkv, const unsigned short* __restrict__ vT,
                 unsigned short* __restrict__ out) {
    // [grp][buf][K=0/V=1][4096] = 64 KB; scratch aliases the whole pool.
    __shared__ __align__(16) unsigned short lds_pool[2][2][2][64 * 64];

    const int tid  = threadIdx.x;
    const int lane = tid & 63;
    const int wv   = tid >> 6;
    const int grp  = wv >> 2;      // K-tile parity
    const int w    = wv & 3;       // q-subpanel (32 rows each)

    const int wgid = blockIdx.x;
    const int xcd  = wgid & 7;
    const int slot = wgid >> 3;          // 0..31
    const int pp   = slot & 7;           // pair index 0..7
    const int g    = (slot >> 3) * 8 + xcd;
    const int head = g & 15;
    const int b    = g >> 4;

    const size_t rowbase = (size_t)b * S_LEN;
    const int hoff = head * DKV;

    const int lr = lane & 15;
    const int lg = lane >> 4;
    const int lk = lg * 8;

    const int krow   = lane >> 3;
    const int kchunk = ((lane & 7) ^ krow) * 8;

    const int xo0 = (lg ^ (lr & 7)) * 8;
    const int xo1 = ((4 + lg) ^ (lr & 7)) * 8;
    const int qlimA = w * 32 + lr - grp * 64;        // mask: kl > qlim
    const int qlimB = qlimA + 16;

    float* scratch = (float*)&lds_pool[0][0][0][0];

    #pragma unroll
    for (int panel = 0; panel < 2; panel++) {
        const int pq = (panel == 0) ? pp : (15 - pp);   // 128-row panel index
        const int q0 = pq * 128;
        const int nt = 2 * pq + 2;
        const int niter = pq + 1;

        s16x8 qf0, qf1, qg0, qg1;
        {
            const unsigned short* qp = qkv + (rowbase + q0 + w * 32 + lr) * (2 * HID) + hoff;
            qf0 = *(const s16x8*)(qp + lk);
            qf1 = *(const s16x8*)(qp + 32 + lk);
            const unsigned short* qq = qp + 16 * (2 * HID);
            qg0 = *(const s16x8*)(qq + lk);
            qg1 = *(const s16x8*)(qq + 32 + lk);
        }

        f32x4 oA[4] = {}, oB[4] = {};
        float lsumA = 0.0f, lsumB = 0.0f;
        int cur = 0;

        // protect pool from previous panel's readers, then prologue stage
        __syncthreads();
        {
            const int j0 = grp * 64;
            #pragma unroll
            for (int l = 0; l < 2; l++) {
                const int r0 = (w * 2 + l) * 8;
                gload_lds16(qkv + (rowbase + j0 + r0 + krow) * (2 * HID) + HID + hoff + kchunk,
                            &lds_pool[grp][0][0][r0 * 64]);
                gload_lds16(vT + ((size_t)b * HID + hoff + r0 + krow) * S_LEN + j0 + kchunk,
                            &lds_pool[grp][0][1][r0 * 64]);
            }
        }

        for (int it = 0; it < niter; it++) {
            const int t = 2 * it + grp;
            __syncthreads();   // drains gloads; buf[cur] ready

            if (t + 2 < nt) {
                const int jn = (t + 2) * 64;
                #pragma unroll
                for (int l = 0; l < 2; l++) {
                    const int r0 = (w * 2 + l) * 8;
                    gload_lds16(qkv + (rowbase + jn + r0 + krow) * (2 * HID) + HID + hoff + kchunk,
                                &lds_pool[grp][cur ^ 1][0][r0 * 64]);
                    gload_lds16(vT + ((size_t)b * HID + hoff + r0 + krow) * S_LEN + jn + kchunk,
                                &lds_pool[grp][cur ^ 1][1][r0 * 64]);
                }
            }

            if (it == niter - 1) {
                attn_tile32<true>(&lds_pool[grp][cur][0][0], &lds_pool[grp][cur][1][0],
                                  qf0, qf1, qg0, qg1, oA, oB, lsumA, lsumB,
                                  lr, lg, xo0, xo1, qlimA, qlimB);
            } else {
                attn_tile32<false>(&lds_pool[grp][cur][0][0], &lds_pool[grp][cur][1][0],
                                   qf0, qf1, qg0, qg1, oA, oB, lsumA, lsumB,
                                   lr, lg, xo0, xo1, qlimA, qlimB);
            }
            cur ^= 1;
        }

        // intra-block combine: group 1 -> LDS scratch (f32), group 0 merges
        __syncthreads();
        const int sbase = (w * 64 + lane) * 35;    // odd stride: conflict-free
        if (grp == 1) {
            #pragma unroll
            for (int dt = 0; dt < 4; dt++)
                #pragma unroll
                for (int r = 0; r < 4; r++) {
                    scratch[sbase + dt * 4 + r]      = oA[dt][r];
                    scratch[sbase + 16 + dt * 4 + r] = oB[dt][r];
                }
            scratch[sbase + 32] = lsumA;
            scratch[sbase + 33] = lsumB;
        }
        __syncthreads();
        if (grp == 0) {
            #pragma unroll
            for (int dt = 0; dt < 4; dt++)
                #pragma unroll
                for (int r = 0; r < 4; r++) {
                    oA[dt][r] += scratch[sbase + dt * 4 + r];
                    oB[dt][r] += scratch[sbase + 16 + dt * 4 + r];
                }
            lsumA += scratch[sbase + 32];
            lsumB += scratch[sbase + 33];
            lsumA += __shfl_xor(lsumA, 16, 64);
            lsumA += __shfl_xor(lsumA, 32, 64);
            lsumB += __shfl_xor(lsumB, 16, 64);
            lsumB += __shfl_xor(lsumB, 32, 64);
            float invlA = 1.0f / lsumA;
            float invlB = 1.0f / lsumB;
            const int qrowA = q0 + w * 32 + lr;
            #pragma unroll
            for (int dt = 0; dt < 4; dt++) {
                s16x4 pkA, pkB;
                #pragma unroll
                for (int r = 0; r < 4; r++) {
                    pkA[r] = (short)f2bf(oA[dt][r] * invlA);
                    pkB[r] = (short)f2bf(oB[dt][r] * invlB);
                }
                *(s16x4*)&out[(rowbase + qrowA) * HID + hoff + dt * 16 + lg * 4]      = pkA;
                *(s16x4*)&out[(rowbase + qrowA + 16) * HID + hoff + dt * 16 + lg * 4] = pkB;
            }
        }
    }
}

extern "C" void kernel_launch(void* const* d_in, const int* in_sizes, int n_in,
                              void* d_out, int out_size, void* d_ws, size_t ws_size,
                              hipStream_t stream) {
    const float* x      = (const float*)d_in[0];
    const float* w_attn = (const float*)d_in[1];
    const float* b_attn = (const float*)d_in[2];
    const float* w_proj = (const float*)d_in[3];
    const float* b_proj = (const float*)d_in[4];
    float* out = (float*)d_out;

    char* ws = (char*)d_ws;
    unsigned short* qkv      = (unsigned short*)(ws);               // 16 MB [M][2H]
    unsigned short* waT      = (unsigned short*)(ws + 16777216);    // 6 MB
    unsigned short* wpT      = (unsigned short*)(ws + 23068672);    // 2 MB
    unsigned short* attn_out = (unsigned short*)(ws + 25165824);    // 8 MB (bf16)
    unsigned short* xb       = (unsigned short*)(ws + 33554432);    // 8 MB (bf16)
    unsigned short* vTr      = (unsigned short*)(ws + 41943040);    // 8 MB (bf16)

    const int M = BATCH * S_LEN;   // 4096

    prep_kernel<<<dim3(6144), 256, 0, stream>>>(x, xb, w_attn, waT, w_proj, wpT);

    gemm_qkv_kernel<<<dim3(3 * HID / 128, M / 128), 256, 0, stream>>>(
        xb, waT, b_attn, qkv, vTr, M, 3 * HID, HID);

    attn_kernel<<<dim3(256), 512, 0, stream>>>(qkv, vTr, attn_out);

    gemm64_kernel<<<dim3(HID / 128, M / 64), 256, 0, stream>>>(
        attn_out, wpT, b_proj, out, M, HID, HID);
}